// Round 8
// baseline (142.952 us; speedup 1.0000x reference)
//
#include <hip/hip_runtime.h>
#include <hip/hip_bf16.h>
#include <hip/hip_cooperative_groups.h>

// Problem constants (from reference)
#define UNITS 512
#define CONN  512
#define SEQL  32

namespace cg = cooperative_groups;

typedef __hip_bfloat16 bf16;
typedef __attribute__((ext_vector_type(8))) short short8;   // 8 bf16 = MFMA A/B frag
typedef __attribute__((ext_vector_type(4))) float floatx4;  // MFMA C/D frag

// out[b,u] = relu( sum_c x[b,c] * kernel[u] * dendriticW[dendrites[u,c], u] + bias[u] )
// == 512^3 GEMM with gather-built weights. fp32 I/O; x,W quantized to bf16 for
// MFMA (absmax 1.95e-3 vs 9.84e-3 threshold, measured R4-R7).
//
// R8: ONE cooperative launch replaces the prep->gemm kernel pair; grid.sync()
// replaces the kernel-boundary drain + second graph-node launch (the ~8-10 us
// residual my per-kernel arithmetic can't account for). Phase bodies are R7's
// measured-best prep and gemm, unchanged.
//   Phase 1: blocks 0-127 build bf16 W (1 unit/wave, dW column staged in LDS);
//            blocks 128-255 convert x -> bf16.
//   Phase 2: 1024 waves (4/block), one 16x16 MFMA tile each, K=512 unrolled.
// Frag layouts (learn_hip m89/m92-verified): A[m=lane&15][k=(lane>>4)*8+j];
// B from W rows (B^T); C/D col=lane&15, row=(lane>>4)*4+reg.

union cv8 { bf16 h[8]; short8 v; };

__global__ __launch_bounds__(256) void dendriter_coop(
    const float* __restrict__ x,     // [512*CONN] fp32
    const float* __restrict__ kern,  // [UNITS] fp32
    const float* __restrict__ dW,    // [SEQL*UNITS] fp32
    const float* __restrict__ bias,  // [UNITS] fp32
    const int*   __restrict__ dend,  // [UNITS*CONN] int32
    bf16* __restrict__ W,            // [UNITS*CONN] bf16 scratch (d_ws)
    bf16* __restrict__ xb,           // [512*CONN] bf16 scratch (d_ws)
    float* __restrict__ out)         // [512*UNITS] fp32
{
    __shared__ float table[4][SEQL];
    const int b = blockIdx.x;        // 0..255 (1 block/CU)
    const int t = threadIdx.x;       // 0..255
    const int wid  = t >> 6;         // wave 0..3
    const int lane = t & 63;

    // ---------------- Phase 1 (R7 prep bodies, re-partitioned) ----------------
    if (b < 128) {
        // W build: one unit per wave.
        const int u = b * 4 + wid;
        if (lane < SEQL)                         // one 32-line gather per wave
            table[wid][lane] = dW[lane * UNITS + u];
        __syncthreads();                         // block-uniform branch: safe

        const int c0 = lane * 8;
        const float kv = kern[u];
        const int4 s0 = ((const int4*)(dend + u * CONN + c0))[0];  // coalesced
        const int4 s1 = ((const int4*)(dend + u * CONN + c0))[1];
        const int segs[8] = {s0.x, s0.y, s0.z, s0.w, s1.x, s1.y, s1.z, s1.w};
        cv8 w;
#pragma unroll
        for (int i = 0; i < 8; ++i)  // LDS lookup: random over 32 banks (~free)
            w.h[i] = __float2bfloat16(kv * table[wid][segs[i]]);
        *(short8*)(W + u * CONN + c0) = w.v;     // 16B coalesced
    } else {
        // x conversion: 32768 threads x 8 floats = 512*512.
        const int t2 = (b - 128) * 256 + t;
        const float4 f0 = ((const float4*)x)[t2 * 2];
        const float4 f1 = ((const float4*)x)[t2 * 2 + 1];
        cv8 a;
        a.h[0] = __float2bfloat16(f0.x); a.h[1] = __float2bfloat16(f0.y);
        a.h[2] = __float2bfloat16(f0.z); a.h[3] = __float2bfloat16(f0.w);
        a.h[4] = __float2bfloat16(f1.x); a.h[5] = __float2bfloat16(f1.y);
        a.h[6] = __float2bfloat16(f1.z); a.h[7] = __float2bfloat16(f1.w);
        *(short8*)(xb + t2 * 8) = a.v;
    }

    __threadfence();                 // device-scope release of W/xb
    cg::this_grid().sync();          // replaces kernel boundary

    // ---------------- Phase 2 (R7 gemm body, tile = b*4 + wid) ----------------
    const int tile = b * 4 + wid;    // 0..1023
    const int ut = (tile & 31) * 16;
    const int bt = (tile >> 5) * 16;
    const int m = lane & 15;
    const int q = lane >> 4;

    const bf16* xrow = xb + (size_t)(bt + m) * CONN + q * 8;
    const bf16* wrow = W  + (size_t)(ut + m) * CONN + q * 8;

    floatx4 acc = {0.f, 0.f, 0.f, 0.f};
#pragma unroll
    for (int k = 0; k < CONN; k += 32) {
        const short8 a = *(const short8*)(xrow + k);
        const short8 bb = *(const short8*)(wrow + k);
        acc = __builtin_amdgcn_mfma_f32_16x16x32_bf16(a, bb, acc, 0, 0, 0);
    }

    const float bu = bias[ut + m];
#pragma unroll
    for (int r = 0; r < 4; ++r) {
        float v = acc[r] + bu;
        v = v > 0.f ? v : 0.f;
        out[(size_t)(bt + q * 4 + r) * UNITS + ut + m] = v;
    }
}

// ---------------- Fallback (ws < 1 MB): R5's proven fused kernel ----------------
__device__ __forceinline__ short8 cvt8(const float* p) {
    const float4 f0 = ((const float4*)p)[0];
    const float4 f1 = ((const float4*)p)[1];
    cv8 a;
    a.h[0] = __float2bfloat16(f0.x); a.h[1] = __float2bfloat16(f0.y);
    a.h[2] = __float2bfloat16(f0.z); a.h[3] = __float2bfloat16(f0.w);
    a.h[4] = __float2bfloat16(f1.x); a.h[5] = __float2bfloat16(f1.y);
    a.h[6] = __float2bfloat16(f1.z); a.h[7] = __float2bfloat16(f1.w);
    return a.v;
}

__global__ __launch_bounds__(256) void dendriter_fused_mfma(
    const float* __restrict__ x, const float* __restrict__ kern,
    const float* __restrict__ dW, const float* __restrict__ bias,
    const int* __restrict__ dend, float* __restrict__ out)
{
    __shared__ short8 wl[16][65];
    const int t  = threadIdx.x;
    const int ut = blockIdx.x * 16;
    const int bt = blockIdx.y * 64;
    {
        const int ul  = t >> 4;
        const int cg0 = (t & 15) * 4;
        const int u   = ut + ul;
        const float kv = kern[u];
        const int4* dp = (const int4*)(dend + u * CONN + cg0 * 8);
#pragma unroll
        for (int j = 0; j < 4; ++j) {
            const int4 s0 = dp[2 * j];
            const int4 s1 = dp[2 * j + 1];
            const int segs[8] = {s0.x, s0.y, s0.z, s0.w, s1.x, s1.y, s1.z, s1.w};
            cv8 w;
#pragma unroll
            for (int i = 0; i < 8; ++i)
                w.h[i] = __float2bfloat16(kv * dW[segs[i] * UNITS + u]);
            const int cg = cg0 + j;
            wl[cg >> 2][ul | ((cg & 3) << 4)] = w.v;
        }
    }
    __syncthreads();

    const int lane = t & 63;
    const int wv   = t >> 6;
    const int m = lane & 15;
    const int q = lane >> 4;
    const int btw = bt + wv * 16;
    const float* xrow = x + (size_t)(btw + m) * CONN + q * 8;
    floatx4 acc = {0.f, 0.f, 0.f, 0.f};
#pragma unroll
    for (int kb = 0; kb < 16; ++kb) {
        const short8 a = cvt8(xrow + kb * 32);
        const short8 bfr = wl[kb][lane];
        acc = __builtin_amdgcn_mfma_f32_16x16x32_bf16(a, bfr, acc, 0, 0, 0);
    }
    const float bu = bias[ut + m];
#pragma unroll
    for (int r = 0; r < 4; ++r) {
        float v = acc[r] + bu;
        v = v > 0.f ? v : 0.f;
        out[(size_t)(btw + q * 4 + r) * UNITS + ut + m] = v;
    }
}

extern "C" void kernel_launch(void* const* d_in, const int* in_sizes, int n_in,
                              void* d_out, int out_size, void* d_ws, size_t ws_size,
                              hipStream_t stream) {
    // setup_inputs() order: x, kernel, dendriticW, bias, dendrites — all fp32
    const float* x    = (const float*)d_in[0];
    const float* kern = (const float*)d_in[1];
    const float* dW   = (const float*)d_in[2];
    const float* bias = (const float*)d_in[3];
    const int*   dend = (const int*)  d_in[4];
    float* out = (float*)d_out;

    const int batch = in_sizes[0] / CONN;                        // 512
    const size_t w_bytes  = (size_t)UNITS * CONN * sizeof(bf16); // 512 KB
    const size_t xb_bytes = (size_t)batch * CONN * sizeof(bf16); // 512 KB

    if (ws_size >= w_bytes + xb_bytes && batch == 512) {
        bf16* W  = (bf16*)d_ws;
        bf16* xb = W + (size_t)UNITS * CONN;
        void* args[] = {(void*)&x, (void*)&kern, (void*)&dW, (void*)&bias,
                        (void*)&dend, (void*)&W, (void*)&xb, (void*)&out};
        hipLaunchCooperativeKernel((const void*)dendriter_coop,
                                   dim3(256), dim3(256), args, 0, stream);
    } else {
        dendriter_fused_mfma<<<dim3(UNITS / 16, batch / 64), 256, 0, stream>>>(
            x, kern, dW, bias, dend, out);
    }
}

// Round 9
// 67.076 us; speedup vs baseline: 2.1312x; 2.1312x over previous
//
#include <hip/hip_runtime.h>
#include <hip/hip_bf16.h>

// Problem constants (from reference)
#define UNITS 512
#define CONN  512
#define SEQL  32

typedef __hip_bfloat16 bf16;
typedef __attribute__((ext_vector_type(8))) short short8;   // 8 bf16 = MFMA A/B frag
typedef __attribute__((ext_vector_type(4))) float floatx4;  // MFMA C/D frag

// out[b,u] = relu( sum_c x[b,c] * kernel[u] * dendriticW[dendrites[u,c], u] + bias[u] )
// == 512^3 GEMM with gather-built weights. fp32 I/O; x,W quantized to bf16 for
// MFMA (absmax 1.95e-3 vs 9.84e-3 threshold, measured R4-R8).
//
// R8 lesson (measured): cg::grid().sync() costs ~60 us on 8-XCD MI355X —
// cooperative fusion is strictly worse than a kernel boundary. Reverted.
//
// Structure = R7 (measured best, 66.6 us) with ONE change: gemm splits K
// across 2 waves per tile (8-MFMA chains, halved load count, 2048 waves =
// 2/SIMD TLP) with an LDS partial-sum combine — attacks the exposed-latency
// term that resisted all prior modeling.

union cv8 { bf16 h[8]; short8 v; };

// ---------------- K1: prep (build W bf16 + convert x to bf16) — R7 verbatim ----------------
__global__ __launch_bounds__(256) void prep(
    const float* __restrict__ kern,  // [UNITS] fp32
    const float* __restrict__ dW,    // [SEQL*UNITS] fp32
    const int*   __restrict__ dend,  // [UNITS*CONN] int32
    const float* __restrict__ x,     // [batch*CONN] fp32
    bf16* __restrict__ W,            // [UNITS*CONN] bf16 out
    bf16* __restrict__ xb,           // [batch*CONN] bf16 out
    int nxthreads)                   // batch*CONN/8
{
    __shared__ float table[4][SEQL];     // per-wave dW column for its unit
    const int tid = blockIdx.x * 256 + threadIdx.x;
    const int WTHREADS = UNITS * (CONN / 8);          // 32768 (blocks 0..127)

    if (tid < WTHREADS) {
        const int u    = tid >> 6;                    // one unit per wave
        const int lane = threadIdx.x & 63;
        const int wid  = threadIdx.x >> 6;
        if (lane < SEQL)                              // one 32-line gather/wave
            table[wid][lane] = dW[lane * UNITS + u];
        __syncthreads();                              // block-uniform path: safe

        const int c0 = lane * 8;
        const float kv = kern[u];
        const int4 s0 = ((const int4*)(dend + u * CONN + c0))[0];  // coalesced
        const int4 s1 = ((const int4*)(dend + u * CONN + c0))[1];
        const int segs[8] = {s0.x, s0.y, s0.z, s0.w, s1.x, s1.y, s1.z, s1.w};
        cv8 w;
#pragma unroll
        for (int i = 0; i < 8; ++i)   // LDS lookup: random over 32 banks (~free)
            w.h[i] = __float2bfloat16(kv * table[wid][segs[i]]);
        *(short8*)(W + u * CONN + c0) = w.v;          // 16B coalesced
    } else {
        __syncthreads();                              // uniform barrier count
        const int t = tid - WTHREADS;                 // blocks 128.. convert x
        if (t < nxthreads) {
            const float4 f0 = ((const float4*)x)[t * 2];
            const float4 f1 = ((const float4*)x)[t * 2 + 1];
            cv8 a;
            a.h[0] = __float2bfloat16(f0.x); a.h[1] = __float2bfloat16(f0.y);
            a.h[2] = __float2bfloat16(f0.z); a.h[3] = __float2bfloat16(f0.w);
            a.h[4] = __float2bfloat16(f1.x); a.h[5] = __float2bfloat16(f1.y);
            a.h[6] = __float2bfloat16(f1.z); a.h[7] = __float2bfloat16(f1.w);
            *(short8*)(xb + t * 8) = a.v;
        }
    }
}

// ---------------- K2: MFMA GEMM, K split across 2 waves/tile ----------------
// A frag: A[m=lane&15][k=(lane>>4)*8+j]; B from W rows (B^T pattern, m92);
// C/D: col=lane&15 (unit), row=(lane>>4)*4+reg (batch)  [m89-verified].
__global__ __launch_bounds__(128) void gemm_mfma_split(
    const bf16*  __restrict__ xb,    // [batch*CONN] bf16
    const bf16*  __restrict__ W,     // [UNITS*CONN] bf16
    const float* __restrict__ bias,  // [UNITS] fp32
    float* __restrict__ out)         // [batch*UNITS] fp32
{
    __shared__ floatx4 part[64];     // wave-1 partial sums, 16B/lane contiguous

    const int t    = threadIdx.x;    // 0..127 (2 waves)
    const int lane = t & 63;
    const int half = t >> 6;         // K-half: 0 -> [0,256), 1 -> [256,512)
    const int ut = blockIdx.x * 16;
    const int bt = blockIdx.y * 16;
    const int m = lane & 15;
    const int q = lane >> 4;

    const bf16* xrow = xb + (size_t)(bt + m) * CONN + half * 256 + q * 8;
    const bf16* wrow = W  + (size_t)(ut + m) * CONN + half * 256 + q * 8;

    floatx4 acc = {0.f, 0.f, 0.f, 0.f};
#pragma unroll
    for (int k = 0; k < 256; k += 32) {          // 8-MFMA chain per wave
        const short8 a = *(const short8*)(xrow + k);
        const short8 b = *(const short8*)(wrow + k);
        acc = __builtin_amdgcn_mfma_f32_16x16x32_bf16(a, b, acc, 0, 0, 0);
    }

    if (half == 1) part[lane] = acc;             // ds_write_b128, conflict-free
    __syncthreads();
    if (half == 0) {
        const floatx4 p = part[lane];            // ds_read_b128, conflict-free
        const float bu = bias[ut + m];
#pragma unroll
        for (int r = 0; r < 4; ++r) {
            float v = acc[r] + p[r] + bu;
            v = v > 0.f ? v : 0.f;
            out[(size_t)(bt + q * 4 + r) * UNITS + ut + m] = v;
        }
    }
}

// ---------------- Fallback (ws < 1 MB): R5's proven fused kernel ----------------
__device__ __forceinline__ short8 cvt8(const float* p) {
    const float4 f0 = ((const float4*)p)[0];
    const float4 f1 = ((const float4*)p)[1];
    cv8 a;
    a.h[0] = __float2bfloat16(f0.x); a.h[1] = __float2bfloat16(f0.y);
    a.h[2] = __float2bfloat16(f0.z); a.h[3] = __float2bfloat16(f0.w);
    a.h[4] = __float2bfloat16(f1.x); a.h[5] = __float2bfloat16(f1.y);
    a.h[6] = __float2bfloat16(f1.z); a.h[7] = __float2bfloat16(f1.w);
    return a.v;
}

__global__ __launch_bounds__(256) void dendriter_fused_mfma(
    const float* __restrict__ x, const float* __restrict__ kern,
    const float* __restrict__ dW, const float* __restrict__ bias,
    const int* __restrict__ dend, float* __restrict__ out)
{
    __shared__ short8 wl[16][65];
    const int t  = threadIdx.x;
    const int ut = blockIdx.x * 16;
    const int bt = blockIdx.y * 64;
    {
        const int ul  = t >> 4;
        const int cg0 = (t & 15) * 4;
        const int u   = ut + ul;
        const float kv = kern[u];
        const int4* dp = (const int4*)(dend + u * CONN + cg0 * 8);
#pragma unroll
        for (int j = 0; j < 4; ++j) {
            const int4 s0 = dp[2 * j];
            const int4 s1 = dp[2 * j + 1];
            const int segs[8] = {s0.x, s0.y, s0.z, s0.w, s1.x, s1.y, s1.z, s1.w};
            cv8 w;
#pragma unroll
            for (int i = 0; i < 8; ++i)
                w.h[i] = __float2bfloat16(kv * dW[segs[i] * UNITS + u]);
            const int cg = cg0 + j;
            wl[cg >> 2][ul | ((cg & 3) << 4)] = w.v;
        }
    }
    __syncthreads();

    const int lane = t & 63;
    const int wv   = t >> 6;
    const int m = lane & 15;
    const int q = lane >> 4;
    const int btw = bt + wv * 16;
    const float* xrow = x + (size_t)(btw + m) * CONN + q * 8;
    floatx4 acc = {0.f, 0.f, 0.f, 0.f};
#pragma unroll
    for (int kb = 0; kb < 16; ++kb) {
        const short8 a = cvt8(xrow + kb * 32);
        const short8 bfr = wl[kb][lane];
        acc = __builtin_amdgcn_mfma_f32_16x16x32_bf16(a, bfr, acc, 0, 0, 0);
    }
    const float bu = bias[ut + m];
#pragma unroll
    for (int r = 0; r < 4; ++r) {
        float v = acc[r] + bu;
        v = v > 0.f ? v : 0.f;
        out[(size_t)(btw + q * 4 + r) * UNITS + ut + m] = v;
    }
}

extern "C" void kernel_launch(void* const* d_in, const int* in_sizes, int n_in,
                              void* d_out, int out_size, void* d_ws, size_t ws_size,
                              hipStream_t stream) {
    // setup_inputs() order: x, kernel, dendriticW, bias, dendrites — all fp32
    const float* x    = (const float*)d_in[0];
    const float* kern = (const float*)d_in[1];
    const float* dW   = (const float*)d_in[2];
    const float* bias = (const float*)d_in[3];
    const int*   dend = (const int*)  d_in[4];
    float* out = (float*)d_out;

    const int batch = in_sizes[0] / CONN;                        // 512
    const size_t w_bytes  = (size_t)UNITS * CONN * sizeof(bf16); // 512 KB
    const size_t xb_bytes = (size_t)batch * CONN * sizeof(bf16); // 512 KB
    const int nxthreads = batch * CONN / 8;

    if (ws_size >= w_bytes + xb_bytes) {  // ws_size call-invariant -> graph-safe
        bf16* W  = (bf16*)d_ws;
        bf16* xb = W + (size_t)UNITS * CONN;
        prep<<<(UNITS * CONN / 8 + nxthreads + 255) / 256, 256, 0, stream>>>(
            kern, dW, dend, x, W, xb, nxthreads);
        gemm_mfma_split<<<dim3(UNITS / 16, batch / 16), 128, 0, stream>>>(
            xb, W, bias, out);
    } else {
        dendriter_fused_mfma<<<dim3(UNITS / 16, batch / 64), 256, 0, stream>>>(
            x, kern, dW, bias, dend, out);
    }
}